// Round 8
// baseline (469.790 us; speedup 1.0000x reference)
//
#include <hip/hip_runtime.h>
#include <math.h>

#define T_TOT 19200
#define HD    64
#define SKIPN 256
#define NLAYER 24
#define LFN   80
#define NB    2
#define NTL   64             // valid t per layer-group block
#define HALO  64             // staged left halo (needs 63)
#define XR    (NTL + HALO)   // 128 staged rows
#define NGT   (T_TOT / NTL)  // 300
#define NOH   32             // t-tile per head block
#define NTH   (T_TOT / NOH)  // 600
#define NCH   (T_TOT / 32)   // 600 G chunks per batch

typedef float  f32x4  __attribute__((ext_vector_type(4)));
typedef __bf16 bf16x8 __attribute__((ext_vector_type(8)));
typedef __bf16 bf16x4 __attribute__((ext_vector_type(4)));

__device__ __forceinline__ f32x4 mfma16(bf16x8 a, bf16x8 b, f32x4 c) {
    return __builtin_amdgcn_mfma_f32_16x16x32_bf16(a, b, c, 0, 0, 0);
}

// ---------------- prep: convert weights to bf16 in MFMA fragment order ----------------
// Fragment order: [...][mtile][ks][lane(64)][j(8)]; row = mtile*16 + (lane&15),
// k = ks*32 + (lane>>4)*8 + j.
__global__ __launch_bounds__(256) void prep_kernel(
    const float* __restrict__ dil_w, const float* __restrict__ skip_w,
    const float* __restrict__ skip_b, const float* __restrict__ res_w,
    const float* __restrict__ out1_w, const float* __restrict__ out2_w,
    __bf16* __restrict__ A1f, __bf16* __restrict__ Asf, __bf16* __restrict__ A3f,
    __bf16* __restrict__ Ao1f, __bf16* __restrict__ Ao2f, float* __restrict__ sbsum)
{
    int idx = blockIdx.x * 256 + threadIdx.x;
    if (idx < 24 * 128 * 128) {
        {   // A1f: l(24) mt(8) ks(4) lane j ; k<64 -> tap(t-d), k>=64 -> tap(t)
            int j = idx & 7, lane = (idx >> 3) & 63, ks = (idx >> 9) & 3;
            int mt = (idx >> 11) & 7, l = idx >> 14;
            int row = mt * 16 + (lane & 15);
            int k   = ks * 32 + (lane >> 4) * 8 + j;
            A1f[idx] = (__bf16)dil_w[((l * 128 + row) * 64 + (k & 63)) * 2 + (k >> 6)];
        }
        {   // Asf: l(24) mt(16) ks(2) lane j
            int j = idx & 7, lane = (idx >> 3) & 63, ks = (idx >> 9) & 1;
            int mt = (idx >> 10) & 15, l = idx >> 14;
            int row = mt * 16 + (lane & 15);
            int k   = ks * 32 + (lane >> 4) * 8 + j;
            Asf[idx] = (__bf16)skip_w[(l * 256 + row) * 64 + k];
        }
    }
    if (idx < 23 * 64 * 64) {   // A3f: l(23) mt(4) ks(2) lane j
        int j = idx & 7, lane = (idx >> 3) & 63, ks = (idx >> 9) & 1;
        int mt = (idx >> 10) & 3, l = idx >> 12;
        int row = mt * 16 + (lane & 15);
        int k   = ks * 32 + (lane >> 4) * 8 + j;
        A3f[idx] = (__bf16)res_w[(l * 64 + row) * 64 + k];
    }
    if (idx < 256 * 256) {      // Ao1f/Ao2f: mt(16) ks(8) lane j
        int j = idx & 7, lane = (idx >> 3) & 63, ks = (idx >> 9) & 7;
        int mt = idx >> 12;
        int row = mt * 16 + (lane & 15);
        int k   = ks * 32 + (lane >> 4) * 8 + j;
        Ao1f[idx] = (__bf16)out1_w[row * 256 + k];
        Ao2f[idx] = (__bf16)out2_w[row * 256 + k];
    }
    if (idx < 256) {
        float s = 0.0f;
        #pragma unroll
        for (int l = 0; l < NLAYER; ++l) s += skip_b[l * 256 + idx];
        sbsum[idx] = s;
    }
}

// ---------------- upsample stage 1 ----------------
__global__ __launch_bounds__(256) void up_kernel(
    const float* __restrict__ lf, const float* __restrict__ up_w,
    const float* __restrict__ up_b, float* __restrict__ y_up)
{
    int idx = blockIdx.x * 256 + threadIdx.x;
    if (idx >= NB * LFN * 256) return;
    int t4 = idx & 255;
    int g  = (idx >> 8) % LFN;
    int b  = idx / (LFN * 256);
    int l = t4 >> 2, k = t4 & 3;
    float acc = up_b[g];
    const float* lfp = lf + (b * 64 + l) * LFN;
    #pragma unroll 8
    for (int f = 0; f < LFN; ++f)
        acc += lfp[f] * up_w[(f * LFN + g) * 4 + k];
    y_up[idx] = acc;
}

// ---------------- upsample stage 2: z[b][o][q] ----------------
__global__ __launch_bounds__(256) void proj_kernel(
    const float* __restrict__ y_up, const float* __restrict__ proj_w,
    const float* __restrict__ proj_b, float* __restrict__ z)
{
    int idx = blockIdx.x * 256 + threadIdx.x;
    if (idx >= NB * 3072 * 256) return;
    int t4 = idx & 255;
    int o  = (idx >> 8) % 3072;
    int b  = idx / (3072 * 256);
    float acc = proj_b[o];
    const float* yp = y_up + b * LFN * 256 + t4;
    const float* wp = proj_w + o * LFN;
    #pragma unroll 8
    for (int g = 0; g < LFN; ++g)
        acc += wp[g] * yp[g * 256];
    z[idx] = acc;
}

// ---------------- transpose cond to zt[b][q][o] and fold dil_b ----------------
__global__ __launch_bounds__(256) void ztrans_kernel(
    const float* __restrict__ z, const float* __restrict__ dil_b,
    float* __restrict__ zt)
{
    __shared__ float tile[32][33];
    const int b  = blockIdx.z;
    const int o0 = blockIdx.x * 32;
    const int q0 = blockIdx.y * 32;
    const int tx = threadIdx.x & 31;
    const int ty = threadIdx.x >> 5;   // 0..7
    #pragma unroll
    for (int k = 0; k < 4; ++k) {
        int o = o0 + ty + k * 8;
        tile[ty + k * 8][tx] = z[((size_t)(b * 3072 + o)) * 256 + q0 + tx];
    }
    __syncthreads();
    #pragma unroll
    for (int k = 0; k < 4; ++k) {
        int q = q0 + ty + k * 8;
        int o = o0 + tx;
        zt[((size_t)(b * 256 + q)) * 3072 + o] = tile[tx][ty + k * 8] + dil_b[o];
    }
}

// ---------------- 6 fused WaveNet layers (one dilation cycle) ----------------
// grid (NGT, NB), 256 thr (4 waves, wave = m-tile), 4 blocks/CU.
__global__ __launch_bounds__(256, 4) void layer_group(
    const float* __restrict__ gold, const float* __restrict__ ew,
    const float* __restrict__ eb,
    const __bf16* __restrict__ xg_in, __bf16* __restrict__ xg_out,
    const float* __restrict__ zt, const float* __restrict__ res_b,
    const __bf16* __restrict__ A1f, const __bf16* __restrict__ A3f,
    __bf16* __restrict__ G, int L0, int first, int last)
{
    __shared__ __bf16 xh[XR][72];   // x, row t0-64+r
    __shared__ __bf16 Gs[XR][72];   // gated
    __shared__ float  zs[3][128];   // cond+bias q-window

    const int b    = blockIdx.y;
    const int tb   = blockIdx.x;
    const int t0   = tb * NTL;
    const int tid  = threadIdx.x;
    const int lane = tid & 63;
    const int w    = tid >> 6;       // m-tile
    const int n16  = lane & 15;
    const int quad = lane >> 4;
    const int q0   = ((t0 - HALO > 0) ? t0 - HALO : 0) / 75;

    bf16x8 z8;
    #pragma unroll
    for (int u = 0; u < 8; ++u) z8[u] = (__bf16)0.0f;

    // ---- stage x tile [t0-64, t0+64) ----
    if (first) {
        for (int idx = tid; idx < XR * 8; idx += 256) {
            int r = idx >> 3, hc = (idx & 7) * 8;
            int t = t0 - HALO + r;
            bf16x8 v = z8;
            if (t >= 0) {
                float gv = gold[b * T_TOT + t];
                #pragma unroll
                for (int u = 0; u < 8; ++u)
                    v[u] = (__bf16)(gv * ew[hc + u] + eb[hc + u]);
            }
            *(bf16x8*)&xh[r][hc] = v;
        }
    } else {
        for (int idx = tid; idx < XR * 8; idx += 256) {
            int r = idx >> 3, hc = (idx & 7) * 8;
            int t = t0 - HALO + r;
            bf16x8 v = (t >= 0)
                ? *(const bf16x8*)&xg_in[((size_t)b * T_TOT + t) * 64 + hc] : z8;
            *(bf16x8*)&xh[r][hc] = v;
        }
    }

    const bf16x8* A1v = (const bf16x8*)A1f;
    const bf16x8* A3v = (const bf16x8*)A3f;
    f32x4 zero4 = {0.0f, 0.0f, 0.0f, 0.0f};
    const int stj[6] = {0, 0, 0, 1, 2, 4};   // first needed n-tile per layer

    for (int j = 0; j < 6; ++j) {
        const int l = L0 + j;
        const int d = 1 << j;

        // stage cond(+bias) for this layer: 3 coalesced 512B rows from zt
        for (int idx = tid; idx < 384; idx += 256) {
            int qq = idx >> 7, oo = idx & 127;
            int q = q0 + qq; if (q > 255) q = 255;
            zs[qq][oo] = zt[((size_t)(b * 256 + q)) * 3072 + l * 128 + oo];
        }
        // A1 fragments for m-tile w (tanh) and w+4 (sigmoid)
        bf16x8 a1a[4], a1b[4];
        #pragma unroll
        for (int ks = 0; ks < 4; ++ks) {
            a1a[ks] = A1v[((l * 8 + w) * 4 + ks) * 64 + lane];
            a1b[ks] = A1v[((l * 8 + 4 + w) * 4 + ks) * 64 + lane];
        }
        __syncthreads();   // A: zs staged + prev res writes done

        // GEMM1 + gate over needed n-tiles
        for (int nt = stj[j]; nt < 8; ++nt) {
            int nn = nt * 16 + n16;
            int rm = (nn >= d) ? nn - d : 0;
            bf16x8 b0 = *(const bf16x8*)&xh[rm][quad * 8];
            bf16x8 b1 = *(const bf16x8*)&xh[rm][32 + quad * 8];
            bf16x8 b2 = *(const bf16x8*)&xh[nn][quad * 8];
            bf16x8 b3 = *(const bf16x8*)&xh[nn][32 + quad * 8];
            f32x4 aa = zero4, ab = zero4;
            aa = mfma16(a1a[0], b0, aa); ab = mfma16(a1b[0], b0, ab);
            aa = mfma16(a1a[1], b1, aa); ab = mfma16(a1b[1], b1, ab);
            aa = mfma16(a1a[2], b2, aa); ab = mfma16(a1b[2], b2, ab);
            aa = mfma16(a1a[3], b3, aa); ab = mfma16(a1b[3], b3, ab);

            int tt = t0 - HALO + nn;
            int qq = ((tt > 0) ? tt : 0) / 75 - q0;
            int o0 = w * 16 + quad * 4;
            f32x4 za = *(const f32x4*)&zs[qq][o0];
            f32x4 zb = *(const f32x4*)&zs[qq][o0 + 64];
            bf16x4 g4;
            #pragma unroll
            for (int r = 0; r < 4; ++r) {
                float ya = aa[r] + za[r];
                float yb = ab[r] + zb[r];
                float th = 1.0f - 2.0f * __builtin_amdgcn_rcpf(__expf(2.0f * ya) + 1.0f);
                float sg = __builtin_amdgcn_rcpf(1.0f + __expf(-yb));
                g4[r] = (__bf16)(th * sg);
            }
            *(bf16x4*)&Gs[nn][o0] = g4;
        }
        __syncthreads();   // B: Gs complete

        // emit G for valid rows [64,128) -> chunked layout [b][tc32][l][t32][h]
        for (int idx = tid; idx < 512; idx += 256) {
            int rr = idx >> 3, hc = (idx & 7) * 8;
            int cb = tb * 2 + (rr >> 5);
            size_t off = ((size_t)(b * NCH + cb) * NLAYER + l) * 2048 + (rr & 31) * 64 + hc;
            *(bf16x8*)&G[off] = *(const bf16x8*)&Gs[HALO + rr][hc];
        }

        // residual: x += res_w @ g + res_b (needed tiles only, in LDS)
        if (l < NLAYER - 1) {
            bf16x8 a3[2];
            #pragma unroll
            for (int ks = 0; ks < 2; ++ks)
                a3[ks] = A3v[((l * 4 + w) * 2 + ks) * 64 + lane];
            int o0 = w * 16 + quad * 4;
            f32x4 rb = *(const f32x4*)&res_b[l * 64 + o0];
            for (int nt = stj[j]; nt < 8; ++nt) {
                int nn = nt * 16 + n16;
                bf16x8 g0 = *(const bf16x8*)&Gs[nn][quad * 8];
                bf16x8 g1 = *(const bf16x8*)&Gs[nn][32 + quad * 8];
                f32x4 ar = zero4;
                ar = mfma16(a3[0], g0, ar);
                ar = mfma16(a3[1], g1, ar);
                bf16x4 xo = *(const bf16x4*)&xh[nn][o0];
                bf16x4 xn;
                #pragma unroll
                for (int r = 0; r < 4; ++r)
                    xn[r] = (__bf16)((float)xo[r] + ar[r] + rb[r]);
                *(bf16x4*)&xh[nn][o0] = xn;
            }
        }
        // next iteration's sync A orders these writes vs next GEMM1 reads
    }

    if (!last) {
        __syncthreads();
        for (int idx = tid; idx < 512; idx += 256) {
            int rr = idx >> 3, hc = (idx & 7) * 8;
            *(bf16x8*)&xg_out[((size_t)b * T_TOT + t0 + rr) * 64 + hc] =
                *(const bf16x8*)&xh[HALO + rr][hc];
        }
    }
}

// ---------------- fused head: skip (K=1536, 3-deep G pipeline) + out1 + out2 + lsm ----
__global__ __launch_bounds__(256, 4) void head_mfma(
    const __bf16* __restrict__ G, const __bf16* __restrict__ Asf,
    const float* __restrict__ sbsum, const __bf16* __restrict__ Ao1f,
    const __bf16* __restrict__ Ao2f, float* __restrict__ out)
{
    __shared__ __bf16 Vs[NOH][264];
    __shared__ float redm[4][2][16];
    __shared__ float reds[4][2][16];

    const int b    = blockIdx.y;
    const int tcb  = blockIdx.x;
    const int t0   = tcb * NOH;
    const int tid  = threadIdx.x;
    const int lane = tid & 63;
    const int w    = tid >> 6;
    const int n16  = lane & 15;
    const int quad = lane >> 4;

    f32x4 zero4 = {0.0f, 0.0f, 0.0f, 0.0f};
    f32x4 acc[4][2];
    #pragma unroll
    for (int mt = 0; mt < 4; ++mt)
        #pragma unroll
        for (int nt = 0; nt < 2; ++nt) acc[mt][nt] = zero4;

    const bf16x8* Asv = (const bf16x8*)Asf;
    const __bf16* Gb  = G + ((size_t)(b * NCH + tcb)) * (NLAYER * 2048);
    const int goff    = (n16 * 64) + (quad * 8);   // within-layer fragment offset

    // phase 1: skip = sum_l skip_w[l] @ g[l]; G fragments pipelined 3 deep
    bf16x8 gq[3][4];
    #pragma unroll
    for (int p = 0; p < 3; ++p) {
        const __bf16* Gl = Gb + p * 2048;
        gq[p][0] = *(const bf16x8*)&Gl[goff];
        gq[p][1] = *(const bf16x8*)&Gl[goff + 1024];
        gq[p][2] = *(const bf16x8*)&Gl[goff + 32];
        gq[p][3] = *(const bf16x8*)&Gl[goff + 1024 + 32];
    }
    #pragma unroll 3
    for (int l = 0; l < NLAYER; ++l) {
        const int cur = l % 3;
        #pragma unroll
        for (int ks = 0; ks < 2; ++ks)
            #pragma unroll
            for (int mt = 0; mt < 4; ++mt) {
                bf16x8 af = Asv[((l * 16 + w * 4 + mt) * 2 + ks) * 64 + lane];
                acc[mt][0] = mfma16(af, gq[cur][ks * 2], acc[mt][0]);
                acc[mt][1] = mfma16(af, gq[cur][ks * 2 + 1], acc[mt][1]);
            }
        if (l + 3 < NLAYER) {
            const __bf16* Gl = Gb + (l + 3) * 2048;
            gq[cur][0] = *(const bf16x8*)&Gl[goff];
            gq[cur][1] = *(const bf16x8*)&Gl[goff + 1024];
            gq[cur][2] = *(const bf16x8*)&Gl[goff + 32];
            gq[cur][3] = *(const bf16x8*)&Gl[goff + 1024 + 32];
        }
    }
    // epilogue: +bias-sum, relu -> Vs
    {
        int s0 = w * 64 + quad * 4;
        #pragma unroll
        for (int mt = 0; mt < 4; ++mt)
            #pragma unroll
            for (int nt = 0; nt < 2; ++nt) {
                bf16x4 v4;
                #pragma unroll
                for (int r = 0; r < 4; ++r)
                    v4[r] = (__bf16)fmaxf(acc[mt][nt][r] + sbsum[s0 + mt * 16 + r], 0.0f);
                *(bf16x4*)&Vs[nt * 16 + n16][s0 + mt * 16] = v4;
            }
    }
    __syncthreads();

    const bf16x8* W1v = (const bf16x8*)Ao1f;
    const bf16x8* W2v = (const bf16x8*)Ao2f;

    // phase 2: h1 = relu(W1 @ v), K=256
    #pragma unroll
    for (int mt = 0; mt < 4; ++mt)
        #pragma unroll
        for (int nt = 0; nt < 2; ++nt) acc[mt][nt] = zero4;
    #pragma unroll
    for (int ks = 0; ks < 8; ++ks) {
        bf16x8 bfr[2];
        #pragma unroll
        for (int nt = 0; nt < 2; ++nt)
            bfr[nt] = *(const bf16x8*)&Vs[nt * 16 + n16][ks * 32 + quad * 8];
        #pragma unroll
        for (int mt = 0; mt < 4; ++mt) {
            bf16x8 af = W1v[((w * 4 + mt) * 8 + ks) * 64 + lane];
            #pragma unroll
            for (int nt = 0; nt < 2; ++nt)
                acc[mt][nt] = mfma16(af, bfr[nt], acc[mt][nt]);
        }
    }
    __syncthreads();
    #pragma unroll
    for (int mt = 0; mt < 4; ++mt)
        #pragma unroll
        for (int nt = 0; nt < 2; ++nt) {
            int o0 = w * 64 + mt * 16 + quad * 4;
            bf16x4 v4;
            #pragma unroll
            for (int r = 0; r < 4; ++r)
                v4[r] = (__bf16)fmaxf(acc[mt][nt][r], 0.0f);
            *(bf16x4*)&Vs[nt * 16 + n16][o0] = v4;
        }
    __syncthreads();

    // phase 3: h2 = W2 @ relu(h1)
    #pragma unroll
    for (int mt = 0; mt < 4; ++mt)
        #pragma unroll
        for (int nt = 0; nt < 2; ++nt) acc[mt][nt] = zero4;
    #pragma unroll
    for (int ks = 0; ks < 8; ++ks) {
        bf16x8 bfr[2];
        #pragma unroll
        for (int nt = 0; nt < 2; ++nt)
            bfr[nt] = *(const bf16x8*)&Vs[nt * 16 + n16][ks * 32 + quad * 8];
        #pragma unroll
        for (int mt = 0; mt < 4; ++mt) {
            bf16x8 af = W2v[((w * 4 + mt) * 8 + ks) * 64 + lane];
            #pragma unroll
            for (int nt = 0; nt < 2; ++nt)
                acc[mt][nt] = mfma16(af, bfr[nt], acc[mt][nt]);
        }
    }

    // log-softmax over 256 channels per column
    float lmax[2], lsum[2];
    #pragma unroll
    for (int nt = 0; nt < 2; ++nt) {
        float m = -1e30f;
        #pragma unroll
        for (int mt = 0; mt < 4; ++mt)
            #pragma unroll
            for (int r = 0; r < 4; ++r) m = fmaxf(m, acc[mt][nt][r]);
        m = fmaxf(m, __shfl_xor(m, 16, 64));
        m = fmaxf(m, __shfl_xor(m, 32, 64));
        lmax[nt] = m;
    }
    if (quad == 0) {
        #pragma unroll
        for (int nt = 0; nt < 2; ++nt) redm[w][nt][n16] = lmax[nt];
    }
    __syncthreads();
    #pragma unroll
    for (int nt = 0; nt < 2; ++nt) {
        float m = redm[0][nt][n16];
        m = fmaxf(m, redm[1][nt][n16]);
        m = fmaxf(m, redm[2][nt][n16]);
        m = fmaxf(m, redm[3][nt][n16]);
        lmax[nt] = m;
        float s = 0.0f;
        #pragma unroll
        for (int mt = 0; mt < 4; ++mt)
            #pragma unroll
            for (int r = 0; r < 4; ++r) s += __expf(acc[mt][nt][r] - m);
        s += __shfl_xor(s, 16, 64);
        s += __shfl_xor(s, 32, 64);
        lsum[nt] = s;
    }
    if (quad == 0) {
        #pragma unroll
        for (int nt = 0; nt < 2; ++nt) reds[w][nt][n16] = lsum[nt];
    }
    __syncthreads();
    #pragma unroll
    for (int nt = 0; nt < 2; ++nt) {
        float s = reds[0][nt][n16] + reds[1][nt][n16] +
                  reds[2][nt][n16] + reds[3][nt][n16];
        float lse = lmax[nt] + logf(s);
        int t = t0 + nt * 16 + n16;
        #pragma unroll
        for (int mt = 0; mt < 4; ++mt)
            #pragma unroll
            for (int r = 0; r < 4; ++r) {
                int o = w * 64 + mt * 16 + quad * 4 + r;
                out[((size_t)(b * SKIPN + o)) * T_TOT + t] = acc[mt][nt][r] - lse;
            }
    }
}

extern "C" void kernel_launch(void* const* d_in, const int* in_sizes, int n_in,
                              void* d_out, int out_size, void* d_ws, size_t ws_size,
                              hipStream_t stream) {
    const float* lf       = (const float*)d_in[0];
    const float* gold     = (const float*)d_in[1];
    const float* embed_w  = (const float*)d_in[2];
    const float* embed_b  = (const float*)d_in[3];
    const float* up_w     = (const float*)d_in[4];
    const float* up_b     = (const float*)d_in[5];
    const float* proj_w   = (const float*)d_in[6];
    const float* proj_b   = (const float*)d_in[7];
    const float* dil_w    = (const float*)d_in[8];
    const float* dil_b    = (const float*)d_in[9];
    const float* skip_w   = (const float*)d_in[10];
    const float* skip_b   = (const float*)d_in[11];
    const float* res_w    = (const float*)d_in[12];
    const float* res_b    = (const float*)d_in[13];
    const float* out1_w   = (const float*)d_in[14];
    const float* out2_w   = (const float*)d_in[15];

    __bf16* A1f  = (__bf16*)d_ws;          // 393216
    __bf16* Asf  = A1f + 393216;           // 393216
    __bf16* A3f  = Asf + 393216;           // 94208
    __bf16* Ao1f = A3f + 94208;            // 65536
    __bf16* Ao2f = Ao1f + 65536;           // 65536
    __bf16* G    = Ao2f + 65536;           // 2*600*24*2048 = 58982400
    __bf16* xga  = G + (size_t)NB * NCH * NLAYER * 2048;   // 2457600
    __bf16* xgb  = xga + (size_t)NB * T_TOT * HD;          // 2457600
    float*  sbsum = (float*)(xgb + (size_t)NB * T_TOT * HD);
    float*  y_up  = sbsum + 256;
    float*  z     = y_up + NB * LFN * 256;                 // 2*3072*256
    float*  zt    = z + NB * 3072 * 256;                   // 2*256*3072

    prep_kernel<<<(24 * 128 * 128 + 255) / 256, 256, 0, stream>>>(
        dil_w, skip_w, skip_b, res_w, out1_w, out2_w,
        A1f, Asf, A3f, Ao1f, Ao2f, sbsum);
    up_kernel  <<<(NB * LFN * 256 + 255) / 256, 256, 0, stream>>>(lf, up_w, up_b, y_up);
    proj_kernel<<<(NB * 3072 * 256) / 256,      256, 0, stream>>>(y_up, proj_w, proj_b, z);
    ztrans_kernel<<<dim3(96, 8, NB), 256, 0, stream>>>(z, dil_b, zt);

    const __bf16* xin[4] = { xga, xga, xgb, xga };
    __bf16*       xout[4] = { xga, xgb, xga, xgb };
    for (int g = 0; g < 4; ++g) {
        layer_group<<<dim3(NGT, NB), 256, 0, stream>>>(
            gold, embed_w, embed_b, xin[g], xout[g],
            zt, res_b, A1f, A3f, G,
            6 * g, (g == 0) ? 1 : 0, (g == 3) ? 1 : 0);
    }

    head_mfma<<<dim3(NTH, NB), 256, 0, stream>>>(G, Asf, sbsum, Ao1f, Ao2f, (float*)d_out);
}

// Round 9
// 443.158 us; speedup vs baseline: 1.0601x; 1.0601x over previous
//
#include <hip/hip_runtime.h>
#include <math.h>

#define T_TOT 19200
#define HD    64
#define SKIPN 256
#define NLAYER 24
#define LFN   80
#define NB    2
#define NTL   128            // valid t per layer-group block
#define HALO  64             // staged left halo (needs 63)
#define XR    (NTL + HALO)   // 192 staged rows
#define NGT   (T_TOT / NTL)  // 150
#define NOH   64             // t-tile per head block
#define NTH   (T_TOT / NOH)  // 300
#define NCH   (T_TOT / 32)   // 600 G chunks per batch

typedef float  f32x4  __attribute__((ext_vector_type(4)));
typedef __bf16 bf16x8 __attribute__((ext_vector_type(8)));
typedef __bf16 bf16x4 __attribute__((ext_vector_type(4)));

__device__ __forceinline__ f32x4 mfma16(bf16x8 a, bf16x8 b, f32x4 c) {
    return __builtin_amdgcn_mfma_f32_16x16x32_bf16(a, b, c, 0, 0, 0);
}

// ---------------- prep: convert weights to bf16 in MFMA fragment order ----------------
// Fragment order: [...][mtile][ks][lane(64)][j(8)]; row = mtile*16 + (lane&15),
// k = ks*32 + (lane>>4)*8 + j.
__global__ __launch_bounds__(256) void prep_kernel(
    const float* __restrict__ dil_w, const float* __restrict__ skip_w,
    const float* __restrict__ skip_b, const float* __restrict__ res_w,
    const float* __restrict__ out1_w, const float* __restrict__ out2_w,
    __bf16* __restrict__ A1f, __bf16* __restrict__ Asf, __bf16* __restrict__ A3f,
    __bf16* __restrict__ Ao1f, __bf16* __restrict__ Ao2f, float* __restrict__ sbsum)
{
    int idx = blockIdx.x * 256 + threadIdx.x;
    if (idx < 24 * 128 * 128) {
        {   // A1f: l(24) mt(8) ks(4) lane j ; k<64 -> tap(t-d), k>=64 -> tap(t)
            int j = idx & 7, lane = (idx >> 3) & 63, ks = (idx >> 9) & 3;
            int mt = (idx >> 11) & 7, l = idx >> 14;
            int row = mt * 16 + (lane & 15);
            int k   = ks * 32 + (lane >> 4) * 8 + j;
            A1f[idx] = (__bf16)dil_w[((l * 128 + row) * 64 + (k & 63)) * 2 + (k >> 6)];
        }
        {   // Asf: l(24) mt(16) ks(2) lane j
            int j = idx & 7, lane = (idx >> 3) & 63, ks = (idx >> 9) & 1;
            int mt = (idx >> 10) & 15, l = idx >> 14;
            int row = mt * 16 + (lane & 15);
            int k   = ks * 32 + (lane >> 4) * 8 + j;
            Asf[idx] = (__bf16)skip_w[(l * 256 + row) * 64 + k];
        }
    }
    if (idx < 23 * 64 * 64) {   // A3f: l(23) mt(4) ks(2) lane j
        int j = idx & 7, lane = (idx >> 3) & 63, ks = (idx >> 9) & 1;
        int mt = (idx >> 10) & 3, l = idx >> 12;
        int row = mt * 16 + (lane & 15);
        int k   = ks * 32 + (lane >> 4) * 8 + j;
        A3f[idx] = (__bf16)res_w[(l * 64 + row) * 64 + k];
    }
    if (idx < 256 * 256) {      // Ao1f/Ao2f: mt(16) ks(8) lane j
        int j = idx & 7, lane = (idx >> 3) & 63, ks = (idx >> 9) & 7;
        int mt = idx >> 12;
        int row = mt * 16 + (lane & 15);
        int k   = ks * 32 + (lane >> 4) * 8 + j;
        Ao1f[idx] = (__bf16)out1_w[row * 256 + k];
        Ao2f[idx] = (__bf16)out2_w[row * 256 + k];
    }
    if (idx < 256) {
        float s = 0.0f;
        #pragma unroll
        for (int l = 0; l < NLAYER; ++l) s += skip_b[l * 256 + idx];
        sbsum[idx] = s;
    }
}

// ---------------- upsample stage 1 ----------------
__global__ __launch_bounds__(256) void up_kernel(
    const float* __restrict__ lf, const float* __restrict__ up_w,
    const float* __restrict__ up_b, float* __restrict__ y_up)
{
    int idx = blockIdx.x * 256 + threadIdx.x;
    if (idx >= NB * LFN * 256) return;
    int t4 = idx & 255;
    int g  = (idx >> 8) % LFN;
    int b  = idx / (LFN * 256);
    int l = t4 >> 2, k = t4 & 3;
    float acc = up_b[g];
    const float* lfp = lf + (b * 64 + l) * LFN;
    #pragma unroll 8
    for (int f = 0; f < LFN; ++f)
        acc += lfp[f] * up_w[(f * LFN + g) * 4 + k];
    y_up[idx] = acc;
}

// ---------------- upsample stage 2: z[b][o][q] ----------------
__global__ __launch_bounds__(256) void proj_kernel(
    const float* __restrict__ y_up, const float* __restrict__ proj_w,
    const float* __restrict__ proj_b, float* __restrict__ z)
{
    int idx = blockIdx.x * 256 + threadIdx.x;
    if (idx >= NB * 3072 * 256) return;
    int t4 = idx & 255;
    int o  = (idx >> 8) % 3072;
    int b  = idx / (3072 * 256);
    float acc = proj_b[o];
    const float* yp = y_up + b * LFN * 256 + t4;
    const float* wp = proj_w + o * LFN;
    #pragma unroll 8
    for (int g = 0; g < LFN; ++g)
        acc += wp[g] * yp[g * 256];
    z[idx] = acc;
}

// ---------------- transpose cond to zt[b][q][o] and fold dil_b ----------------
__global__ __launch_bounds__(256) void ztrans_kernel(
    const float* __restrict__ z, const float* __restrict__ dil_b,
    float* __restrict__ zt)
{
    __shared__ float tile[32][33];
    const int b  = blockIdx.z;
    const int o0 = blockIdx.x * 32;
    const int q0 = blockIdx.y * 32;
    const int tx = threadIdx.x & 31;
    const int ty = threadIdx.x >> 5;   // 0..7
    #pragma unroll
    for (int k = 0; k < 4; ++k) {
        int o = o0 + ty + k * 8;
        tile[ty + k * 8][tx] = z[((size_t)(b * 3072 + o)) * 256 + q0 + tx];
    }
    __syncthreads();
    #pragma unroll
    for (int k = 0; k < 4; ++k) {
        int q = q0 + ty + k * 8;
        int o = o0 + tx;
        zt[((size_t)(b * 256 + q)) * 3072 + o] = tile[tx][ty + k * 8] + dil_b[o];
    }
}

// ---------------- 6 fused WaveNet layers (one dilation cycle) ----------------
// grid (NGT, NB), 512 thr (8 waves). Wave w: wm = w&3 owns m-tile wm; wg = w>>2
// owns n-tiles [wg*6, wg*6+6). Halo cols degrade 2^j-1 per layer.
__global__ __launch_bounds__(512, 4) void layer_group(
    const float* __restrict__ gold, const float* __restrict__ ew,
    const float* __restrict__ eb,
    const __bf16* __restrict__ xg_in, __bf16* __restrict__ xg_out,
    const float* __restrict__ zt, const float* __restrict__ res_b,
    const __bf16* __restrict__ A1f, const __bf16* __restrict__ A3f,
    __bf16* __restrict__ G, int L0, int first, int last)
{
    __shared__ __bf16 xh[XR][72];   // x, row t0-64+r
    __shared__ __bf16 Gs[XR][72];   // gated
    __shared__ float  zs[4][128];   // cond+bias q-window

    const int b    = blockIdx.y;
    const int tb   = blockIdx.x;
    const int t0   = tb * NTL;
    const int tid  = threadIdx.x;
    const int lane = tid & 63;
    const int w    = tid >> 6;       // 0..7
    const int wm   = w & 3;          // m-tile
    const int wg   = w >> 2;         // n-half
    const int n16  = lane & 15;
    const int quad = lane >> 4;
    const int q0   = ((t0 - HALO > 0) ? t0 - HALO : 0) / 75;

    bf16x8 z8;
    #pragma unroll
    for (int u = 0; u < 8; ++u) z8[u] = (__bf16)0.0f;

    // ---- stage x tile [t0-64, t0+128) ----
    if (first) {
        for (int idx = tid; idx < XR * 8; idx += 512) {
            int r = idx >> 3, hc = (idx & 7) * 8;
            int t = t0 - HALO + r;
            bf16x8 v = z8;
            if (t >= 0) {
                float gv = gold[b * T_TOT + t];
                #pragma unroll
                for (int u = 0; u < 8; ++u)
                    v[u] = (__bf16)(gv * ew[hc + u] + eb[hc + u]);
            }
            *(bf16x8*)&xh[r][hc] = v;
        }
    } else {
        for (int idx = tid; idx < XR * 8; idx += 512) {
            int r = idx >> 3, hc = (idx & 7) * 8;
            int t = t0 - HALO + r;
            bf16x8 v = (t >= 0)
                ? *(const bf16x8*)&xg_in[((size_t)b * T_TOT + t) * 64 + hc] : z8;
            *(bf16x8*)&xh[r][hc] = v;
        }
    }

    const bf16x8* A1v = (const bf16x8*)A1f;
    const bf16x8* A3v = (const bf16x8*)A3f;
    f32x4 zero4 = {0.0f, 0.0f, 0.0f, 0.0f};

    for (int j = 0; j < 6; ++j) {
        const int l = L0 + j;
        const int d = 1 << j;

        // stage cond(+bias): 4 coalesced 512B rows from zt (512 threads = 4x128)
        {
            int qq = tid >> 7, oo = tid & 127;
            int q = q0 + qq; if (q > 255) q = 255;
            zs[qq][oo] = zt[((size_t)(b * 256 + q)) * 3072 + l * 128 + oo];
        }
        // A1 fragments for m-tile wm (tanh rows) and wm+4 (sigmoid rows)
        bf16x8 a1a[4], a1b[4];
        #pragma unroll
        for (int ks = 0; ks < 4; ++ks) {
            a1a[ks] = A1v[((l * 8 + wm) * 4 + ks) * 64 + lane];
            a1b[ks] = A1v[((l * 8 + 4 + wm) * 4 + ks) * 64 + lane];
        }
        __syncthreads();   // A: zs staged + prev-layer res / x staging done

        // GEMM1 + gate over this wave's 6 n-tiles
        #pragma unroll
        for (int nt0 = 0; nt0 < 6; ++nt0) {
            int nt = wg * 6 + nt0;
            int nn = nt * 16 + n16;
            int rm = (nn >= d) ? nn - d : 0;
            bf16x8 b0 = *(const bf16x8*)&xh[rm][quad * 8];
            bf16x8 b1 = *(const bf16x8*)&xh[rm][32 + quad * 8];
            bf16x8 b2 = *(const bf16x8*)&xh[nn][quad * 8];
            bf16x8 b3 = *(const bf16x8*)&xh[nn][32 + quad * 8];
            f32x4 aa = zero4, ab = zero4;
            aa = mfma16(a1a[0], b0, aa); ab = mfma16(a1b[0], b0, ab);
            aa = mfma16(a1a[1], b1, aa); ab = mfma16(a1b[1], b1, ab);
            aa = mfma16(a1a[2], b2, aa); ab = mfma16(a1b[2], b2, ab);
            aa = mfma16(a1a[3], b3, aa); ab = mfma16(a1b[3], b3, ab);

            int tt = t0 - HALO + nn;
            int qq = ((tt > 0) ? tt : 0) / 75 - q0;
            int o0 = wm * 16 + quad * 4;
            f32x4 za = *(const f32x4*)&zs[qq][o0];
            f32x4 zb = *(const f32x4*)&zs[qq][o0 + 64];
            bf16x4 g4;
            #pragma unroll
            for (int r = 0; r < 4; ++r) {
                float ya = aa[r] + za[r];
                float yb = ab[r] + zb[r];
                float th = 1.0f - 2.0f * __builtin_amdgcn_rcpf(__expf(2.0f * ya) + 1.0f);
                float sg = __builtin_amdgcn_rcpf(1.0f + __expf(-yb));
                g4[r] = (__bf16)(th * sg);
            }
            *(bf16x4*)&Gs[nn][o0] = g4;
        }
        __syncthreads();   // B: Gs complete

        // emit G for valid cols [t0, t0+128), chunked layout [b][tc32][l][t32][h]
        {
            __bf16* Gl = G + (((size_t)(b * NCH + tb * 4)) * NLAYER + l) * 2048;
            for (int idx = tid; idx < 128 * 8; idx += 512) {
                int rr = idx >> 3, hc = (idx & 7) * 8;
                size_t off = (size_t)(rr >> 5) * (NLAYER * 2048) + (rr & 31) * 64 + hc;
                *(bf16x8*)&Gl[off] = *(const bf16x8*)&Gs[HALO + rr][hc];
            }
        }

        // residual: x += res_w @ g + res_b (this wave's n-tiles, in LDS)
        if (l < NLAYER - 1) {
            bf16x8 a3[2];
            #pragma unroll
            for (int ks = 0; ks < 2; ++ks)
                a3[ks] = A3v[((l * 4 + wm) * 2 + ks) * 64 + lane];
            int o0 = wm * 16 + quad * 4;
            f32x4 rb = *(const f32x4*)&res_b[l * 64 + o0];
            #pragma unroll
            for (int nt0 = 0; nt0 < 6; ++nt0) {
                int nn = (wg * 6 + nt0) * 16 + n16;
                bf16x8 g0 = *(const bf16x8*)&Gs[nn][quad * 8];
                bf16x8 g1 = *(const bf16x8*)&Gs[nn][32 + quad * 8];
                f32x4 ar = zero4;
                ar = mfma16(a3[0], g0, ar);
                ar = mfma16(a3[1], g1, ar);
                bf16x4 xo = *(const bf16x4*)&xh[nn][o0];
                bf16x4 xn;
                #pragma unroll
                for (int r = 0; r < 4; ++r)
                    xn[r] = (__bf16)((float)xo[r] + ar[r] + rb[r]);
                *(bf16x4*)&xh[nn][o0] = xn;
            }
        }
        // next iteration's sync A orders these writes vs next GEMM1 reads
    }

    if (!last) {
        __syncthreads();
        for (int idx = tid; idx < 128 * 8; idx += 512) {
            int rr = idx >> 3, hc = (idx & 7) * 8;
            *(bf16x8*)&xg_out[((size_t)b * T_TOT + t0 + rr) * 64 + hc] =
                *(const bf16x8*)&xh[HALO + rr][hc];
        }
    }
}

// ---------------- fused head: skip (K=1536) + out1 + out2 + log-softmax ----------------
// grid (NTH, NB), 512 thr (8 waves). Wave w owns rows [w*32, w*32+32) of each GEMM;
// N=64 per block halves per-element A-weight re-streaming vs NOH=32.
__global__ __launch_bounds__(512, 2) void head_mfma(
    const __bf16* __restrict__ G, const __bf16* __restrict__ Asf,
    const float* __restrict__ sbsum, const __bf16* __restrict__ Ao1f,
    const __bf16* __restrict__ Ao2f, float* __restrict__ out)
{
    __shared__ __bf16 Vs[NOH][264];
    __shared__ float redm[8][4][16];
    __shared__ float reds[8][4][16];

    const int b    = blockIdx.y;
    const int xb   = blockIdx.x;
    const int t0   = xb * NOH;
    const int tid  = threadIdx.x;
    const int lane = tid & 63;
    const int w    = tid >> 6;       // 0..7
    const int n16  = lane & 15;
    const int quad = lane >> 4;

    f32x4 zero4 = {0.0f, 0.0f, 0.0f, 0.0f};
    f32x4 acc[2][4];
    #pragma unroll
    for (int mt = 0; mt < 2; ++mt)
        #pragma unroll
        for (int nt = 0; nt < 4; ++nt) acc[mt][nt] = zero4;

    const bf16x8* Asv = (const bf16x8*)Asf;
    const __bf16* Gc0 = G + ((size_t)(b * NCH + xb * 2) * NLAYER) * 2048;
    const __bf16* Gc1 = Gc0 + (size_t)NLAYER * 2048;

    // phase 1: skip = sum_l skip_w[l] @ g[l]  (K = 24*64)
    for (int l = 0; l < NLAYER; ++l) {
        bf16x8 bfr[2][4];
        #pragma unroll
        for (int ks = 0; ks < 2; ++ks) {
            #pragma unroll
            for (int nt = 0; nt < 4; ++nt) {
                const __bf16* base = ((nt < 2) ? Gc0 : Gc1) + l * 2048;
                bfr[ks][nt] = *(const bf16x8*)
                    &base[((nt & 1) * 16 + n16) * 64 + ks * 32 + quad * 8];
            }
        }
        #pragma unroll
        for (int ks = 0; ks < 2; ++ks)
            #pragma unroll
            for (int mt = 0; mt < 2; ++mt) {
                bf16x8 af = Asv[((l * 16 + w * 2 + mt) * 2 + ks) * 64 + lane];
                #pragma unroll
                for (int nt = 0; nt < 4; ++nt)
                    acc[mt][nt] = mfma16(af, bfr[ks][nt], acc[mt][nt]);
            }
    }
    // epilogue: +bias-sum, relu -> Vs[t][s]
    #pragma unroll
    for (int mt = 0; mt < 2; ++mt) {
        int s0 = (w * 2 + mt) * 16 + quad * 4;
        f32x4 sb = *(const f32x4*)&sbsum[s0];
        #pragma unroll
        for (int nt = 0; nt < 4; ++nt) {
            bf16x4 v4;
            #pragma unroll
            for (int r = 0; r < 4; ++r)
                v4[r] = (__bf16)fmaxf(acc[mt][nt][r] + sb[r], 0.0f);
            *(bf16x4*)&Vs[nt * 16 + n16][s0] = v4;
        }
    }
    __syncthreads();

    const bf16x8* W1v = (const bf16x8*)Ao1f;
    const bf16x8* W2v = (const bf16x8*)Ao2f;

    // phase 2: h1 = relu(W1 @ v), K=256
    #pragma unroll
    for (int mt = 0; mt < 2; ++mt)
        #pragma unroll
        for (int nt = 0; nt < 4; ++nt) acc[mt][nt] = zero4;
    #pragma unroll
    for (int ks = 0; ks < 8; ++ks) {
        bf16x8 bfr[4];
        #pragma unroll
        for (int nt = 0; nt < 4; ++nt)
            bfr[nt] = *(const bf16x8*)&Vs[nt * 16 + n16][ks * 32 + quad * 8];
        #pragma unroll
        for (int mt = 0; mt < 2; ++mt) {
            bf16x8 af = W1v[((w * 2 + mt) * 8 + ks) * 64 + lane];
            #pragma unroll
            for (int nt = 0; nt < 4; ++nt)
                acc[mt][nt] = mfma16(af, bfr[nt], acc[mt][nt]);
        }
    }
    __syncthreads();   // all Vs reads done; safe to overwrite
    #pragma unroll
    for (int mt = 0; mt < 2; ++mt) {
        int o0 = (w * 2 + mt) * 16 + quad * 4;
        #pragma unroll
        for (int nt = 0; nt < 4; ++nt) {
            bf16x4 v4;
            #pragma unroll
            for (int r = 0; r < 4; ++r)
                v4[r] = (__bf16)fmaxf(acc[mt][nt][r], 0.0f);
            *(bf16x4*)&Vs[nt * 16 + n16][o0] = v4;
        }
    }
    __syncthreads();

    // phase 3: h2 = W2 @ relu(h1)
    #pragma unroll
    for (int mt = 0; mt < 2; ++mt)
        #pragma unroll
        for (int nt = 0; nt < 4; ++nt) acc[mt][nt] = zero4;
    #pragma unroll
    for (int ks = 0; ks < 8; ++ks) {
        bf16x8 bfr[4];
        #pragma unroll
        for (int nt = 0; nt < 4; ++nt)
            bfr[nt] = *(const bf16x8*)&Vs[nt * 16 + n16][ks * 32 + quad * 8];
        #pragma unroll
        for (int mt = 0; mt < 2; ++mt) {
            bf16x8 af = W2v[((w * 2 + mt) * 8 + ks) * 64 + lane];
            #pragma unroll
            for (int nt = 0; nt < 4; ++nt)
                acc[mt][nt] = mfma16(af, bfr[nt], acc[mt][nt]);
        }
    }

    // log-softmax over 256 channels per column (2 mt x 4 r x quad within wave, x8 waves)
    float lmax[4], lsum[4];
    #pragma unroll
    for (int nt = 0; nt < 4; ++nt) {
        float m = -1e30f;
        #pragma unroll
        for (int mt = 0; mt < 2; ++mt)
            #pragma unroll
            for (int r = 0; r < 4; ++r) m = fmaxf(m, acc[mt][nt][r]);
        m = fmaxf(m, __shfl_xor(m, 16, 64));
        m = fmaxf(m, __shfl_xor(m, 32, 64));
        lmax[nt] = m;
    }
    if (quad == 0) {
        #pragma unroll
        for (int nt = 0; nt < 4; ++nt) redm[w][nt][n16] = lmax[nt];
    }
    __syncthreads();
    #pragma unroll
    for (int nt = 0; nt < 4; ++nt) {
        float m = redm[0][nt][n16];
        #pragma unroll
        for (int ww = 1; ww < 8; ++ww) m = fmaxf(m, redm[ww][nt][n16]);
        lmax[nt] = m;
        float s = 0.0f;
        #pragma unroll
        for (int mt = 0; mt < 2; ++mt)
            #pragma unroll
            for (int r = 0; r < 4; ++r) s += __expf(acc[mt][nt][r] - m);
        s += __shfl_xor(s, 16, 64);
        s += __shfl_xor(s, 32, 64);
        lsum[nt] = s;
    }
    if (quad == 0) {
        #pragma unroll
        for (int nt = 0; nt < 4; ++nt) reds[w][nt][n16] = lsum[nt];
    }
    __syncthreads();
    #pragma unroll
    for (int nt = 0; nt < 4; ++nt) {
        float s = reds[0][nt][n16];
        #pragma unroll
        for (int ww = 1; ww < 8; ++ww) s += reds[ww][nt][n16];
        float lse = lmax[nt] + logf(s);
        int t = t0 + nt * 16 + n16;
        #pragma unroll
        for (int mt = 0; mt < 2; ++mt)
            #pragma unroll
            for (int r = 0; r < 4; ++r) {
                int o = (w * 2 + mt) * 16 + quad * 4 + r;
                out[((size_t)(b * SKIPN + o)) * T_TOT + t] = acc[mt][nt][r] - lse;
            }
    }
}

extern "C" void kernel_launch(void* const* d_in, const int* in_sizes, int n_in,
                              void* d_out, int out_size, void* d_ws, size_t ws_size,
                              hipStream_t stream) {
    const float* lf       = (const float*)d_in[0];
    const float* gold     = (const float*)d_in[1];
    const float* embed_w  = (const float*)d_in[2];
    const float* embed_b  = (const float*)d_in[3];
    const float* up_w     = (const float*)d_in[4];
    const float* up_b     = (const float*)d_in[5];
    const float* proj_w   = (const float*)d_in[6];
    const float* proj_b   = (const float*)d_in[7];
    const float* dil_w    = (const float*)d_in[8];
    const float* dil_b    = (const float*)d_in[9];
    const float* skip_w   = (const float*)d_in[10];
    const float* skip_b   = (const float*)d_in[11];
    const float* res_w    = (const float*)d_in[12];
    const float* res_b    = (const float*)d_in[13];
    const float* out1_w   = (const float*)d_in[14];
    const float* out2_w   = (const float*)d_in[15];

    __bf16* A1f  = (__bf16*)d_ws;          // 393216
    __bf16* Asf  = A1f + 393216;           // 393216
    __bf16* A3f  = Asf + 393216;           // 94208
    __bf16* Ao1f = A3f + 94208;            // 65536
    __bf16* Ao2f = Ao1f + 65536;           // 65536
    __bf16* G    = Ao2f + 65536;           // 2*600*24*2048 = 58982400
    __bf16* xga  = G + (size_t)NB * NCH * NLAYER * 2048;   // 2457600
    __bf16* xgb  = xga + (size_t)NB * T_TOT * HD;          // 2457600
    float*  sbsum = (float*)(xgb + (size_t)NB * T_TOT * HD);
    float*  y_up  = sbsum + 256;
    float*  z     = y_up + NB * LFN * 256;                 // 2*3072*256
    float*  zt    = z + NB * 3072 * 256;                   // 2*256*3072

    prep_kernel<<<(24 * 128 * 128 + 255) / 256, 256, 0, stream>>>(
        dil_w, skip_w, skip_b, res_w, out1_w, out2_w,
        A1f, Asf, A3f, Ao1f, Ao2f, sbsum);
    up_kernel  <<<(NB * LFN * 256 + 255) / 256, 256, 0, stream>>>(lf, up_w, up_b, y_up);
    proj_kernel<<<(NB * 3072 * 256) / 256,      256, 0, stream>>>(y_up, proj_w, proj_b, z);
    ztrans_kernel<<<dim3(96, 8, NB), 256, 0, stream>>>(z, dil_b, zt);

    const __bf16* xin[4] = { xga, xga, xgb, xga };
    __bf16*       xout[4] = { xga, xgb, xga, xgb };
    for (int g = 0; g < 4; ++g) {
        layer_group<<<dim3(NGT, NB), 512, 0, stream>>>(
            gold, embed_w, embed_b, xin[g], xout[g],
            zt, res_b, A1f, A3f, G,
            6 * g, (g == 0) ? 1 : 0, (g == 3) ? 1 : 0);
    }

    head_mfma<<<dim3(NTH, NB), 512, 0, stream>>>(G, Asf, sbsum, Ao1f, Ao2f, (float*)d_out);
}

// Round 10
// 360.889 us; speedup vs baseline: 1.3018x; 1.2280x over previous
//
#include <hip/hip_runtime.h>
#include <math.h>

#define T_TOT 19200
#define HD    64
#define SKIPN 256
#define NLAYER 24
#define LFN   80
#define NB    2
#define NTL   64             // valid t per layer-group block
#define HALO  64             // staged left halo (needs 63)
#define XR    (NTL + HALO)   // 128 staged rows
#define NGT   (T_TOT / NTL)  // 300
#define NOH   32             // t-tile per head block
#define NTH   (T_TOT / NOH)  // 600
#define PSTRIDE ((size_t)NB * SKIPN * T_TOT)   // elems per skip partial

typedef float  f32x4  __attribute__((ext_vector_type(4)));
typedef __bf16 bf16x8 __attribute__((ext_vector_type(8)));
typedef __bf16 bf16x4 __attribute__((ext_vector_type(4)));

__device__ __forceinline__ f32x4 mfma16(bf16x8 a, bf16x8 b, f32x4 c) {
    return __builtin_amdgcn_mfma_f32_16x16x32_bf16(a, b, c, 0, 0, 0);
}

// ---------------- prep: convert weights to bf16 in MFMA fragment order ----------------
// Fragment order: [...][mtile][ks][lane(64)][j(8)]; row = mtile*16 + (lane&15),
// k = ks*32 + (lane>>4)*8 + j.
__global__ __launch_bounds__(256) void prep_kernel(
    const float* __restrict__ dil_w, const float* __restrict__ skip_w,
    const float* __restrict__ skip_b, const float* __restrict__ res_w,
    const float* __restrict__ out1_w, const float* __restrict__ out2_w,
    __bf16* __restrict__ A1f, __bf16* __restrict__ Asf, __bf16* __restrict__ A3f,
    __bf16* __restrict__ Ao1f, __bf16* __restrict__ Ao2f, float* __restrict__ sbsum)
{
    int idx = blockIdx.x * 256 + threadIdx.x;
    if (idx < 24 * 128 * 128) {
        {   // A1f: l(24) mt(8) ks(4) lane j ; k<64 -> tap(t-d), k>=64 -> tap(t)
            int j = idx & 7, lane = (idx >> 3) & 63, ks = (idx >> 9) & 3;
            int mt = (idx >> 11) & 7, l = idx >> 14;
            int row = mt * 16 + (lane & 15);
            int k   = ks * 32 + (lane >> 4) * 8 + j;
            A1f[idx] = (__bf16)dil_w[((l * 128 + row) * 64 + (k & 63)) * 2 + (k >> 6)];
        }
        {   // Asf: l(24) mt(16) ks(2) lane j
            int j = idx & 7, lane = (idx >> 3) & 63, ks = (idx >> 9) & 1;
            int mt = (idx >> 10) & 15, l = idx >> 14;
            int row = mt * 16 + (lane & 15);
            int k   = ks * 32 + (lane >> 4) * 8 + j;
            Asf[idx] = (__bf16)skip_w[(l * 256 + row) * 64 + k];
        }
    }
    if (idx < 23 * 64 * 64) {   // A3f: l(23) mt(4) ks(2) lane j
        int j = idx & 7, lane = (idx >> 3) & 63, ks = (idx >> 9) & 1;
        int mt = (idx >> 10) & 3, l = idx >> 12;
        int row = mt * 16 + (lane & 15);
        int k   = ks * 32 + (lane >> 4) * 8 + j;
        A3f[idx] = (__bf16)res_w[(l * 64 + row) * 64 + k];
    }
    if (idx < 256 * 256) {      // Ao1f/Ao2f: mt(16) ks(8) lane j
        int j = idx & 7, lane = (idx >> 3) & 63, ks = (idx >> 9) & 7;
        int mt = idx >> 12;
        int row = mt * 16 + (lane & 15);
        int k   = ks * 32 + (lane >> 4) * 8 + j;
        Ao1f[idx] = (__bf16)out1_w[row * 256 + k];
        Ao2f[idx] = (__bf16)out2_w[row * 256 + k];
    }
    if (idx < 256) {
        float s = 0.0f;
        #pragma unroll
        for (int l = 0; l < NLAYER; ++l) s += skip_b[l * 256 + idx];
        sbsum[idx] = s;
    }
}

// ---------------- upsample stage 1 ----------------
__global__ __launch_bounds__(256) void up_kernel(
    const float* __restrict__ lf, const float* __restrict__ up_w,
    const float* __restrict__ up_b, float* __restrict__ y_up)
{
    int idx = blockIdx.x * 256 + threadIdx.x;
    if (idx >= NB * LFN * 256) return;
    int t4 = idx & 255;
    int g  = (idx >> 8) % LFN;
    int b  = idx / (LFN * 256);
    int l = t4 >> 2, k = t4 & 3;
    float acc = up_b[g];
    const float* lfp = lf + (b * 64 + l) * LFN;
    #pragma unroll 8
    for (int f = 0; f < LFN; ++f)
        acc += lfp[f] * up_w[(f * LFN + g) * 4 + k];
    y_up[idx] = acc;
}

// ---------------- upsample stage 2: z[b][o][q] ----------------
__global__ __launch_bounds__(256) void proj_kernel(
    const float* __restrict__ y_up, const float* __restrict__ proj_w,
    const float* __restrict__ proj_b, float* __restrict__ z)
{
    int idx = blockIdx.x * 256 + threadIdx.x;
    if (idx >= NB * 3072 * 256) return;
    int t4 = idx & 255;
    int o  = (idx >> 8) % 3072;
    int b  = idx / (3072 * 256);
    float acc = proj_b[o];
    const float* yp = y_up + b * LFN * 256 + t4;
    const float* wp = proj_w + o * LFN;
    #pragma unroll 8
    for (int g = 0; g < LFN; ++g)
        acc += wp[g] * yp[g * 256];
    z[idx] = acc;
}

// ---------------- transpose cond to zt[b][q][o] and fold dil_b ----------------
__global__ __launch_bounds__(256) void ztrans_kernel(
    const float* __restrict__ z, const float* __restrict__ dil_b,
    float* __restrict__ zt)
{
    __shared__ float tile[32][33];
    const int b  = blockIdx.z;
    const int o0 = blockIdx.x * 32;
    const int q0 = blockIdx.y * 32;
    const int tx = threadIdx.x & 31;
    const int ty = threadIdx.x >> 5;   // 0..7
    #pragma unroll
    for (int k = 0; k < 4; ++k) {
        int o = o0 + ty + k * 8;
        tile[ty + k * 8][tx] = z[((size_t)(b * 3072 + o)) * 256 + q0 + tx];
    }
    __syncthreads();
    #pragma unroll
    for (int k = 0; k < 4; ++k) {
        int q = q0 + ty + k * 8;
        int o = o0 + tx;
        zt[((size_t)(b * 256 + q)) * 3072 + o] = tile[tx][ty + k * 8] + dil_b[o];
    }
}

// ---------------- 6 fused WaveNet layers + fused skip accumulation ----------------
// grid (NGT, NB), 256 thr (4 waves, wave = m-tile). Skip rows [wm*64, wm*64+64)
// accumulate in registers across the 6 layers; one bf16 partial written at end.
__global__ __launch_bounds__(256) void layer_group(
    const float* __restrict__ gold, const float* __restrict__ ew,
    const float* __restrict__ eb,
    const __bf16* __restrict__ xg_in, __bf16* __restrict__ xg_out,
    const float* __restrict__ zt, const float* __restrict__ res_b,
    const __bf16* __restrict__ A1f, const __bf16* __restrict__ A3f,
    const __bf16* __restrict__ Asf, __bf16* __restrict__ skipp_g,
    int L0, int first, int last)
{
    __shared__ __bf16 xh[XR][72];   // x, row t0-64+r
    __shared__ __bf16 Gs[XR][72];   // gated
    __shared__ float  zs[3][128];   // cond+bias q-window

    const int b    = blockIdx.y;
    const int tb   = blockIdx.x;
    const int t0   = tb * NTL;
    const int tid  = threadIdx.x;
    const int lane = tid & 63;
    const int wm   = tid >> 6;       // m-tile / skip row group
    const int n16  = lane & 15;
    const int quad = lane >> 4;
    const int q0   = ((t0 - HALO > 0) ? t0 - HALO : 0) / 75;

    bf16x8 z8;
    #pragma unroll
    for (int u = 0; u < 8; ++u) z8[u] = (__bf16)0.0f;

    // ---- stage x tile [t0-64, t0+64) ----
    if (first) {
        for (int idx = tid; idx < XR * 8; idx += 256) {
            int r = idx >> 3, hc = (idx & 7) * 8;
            int t = t0 - HALO + r;
            bf16x8 v = z8;
            if (t >= 0) {
                float gv = gold[b * T_TOT + t];
                #pragma unroll
                for (int u = 0; u < 8; ++u)
                    v[u] = (__bf16)(gv * ew[hc + u] + eb[hc + u]);
            }
            *(bf16x8*)&xh[r][hc] = v;
        }
    } else {
        for (int idx = tid; idx < XR * 8; idx += 256) {
            int r = idx >> 3, hc = (idx & 7) * 8;
            int t = t0 - HALO + r;
            bf16x8 v = (t >= 0)
                ? *(const bf16x8*)&xg_in[((size_t)b * T_TOT + t) * 64 + hc] : z8;
            *(bf16x8*)&xh[r][hc] = v;
        }
    }

    const bf16x8* A1v = (const bf16x8*)A1f;
    const bf16x8* A3v = (const bf16x8*)A3f;
    const bf16x8* Asv = (const bf16x8*)Asf;
    f32x4 zero4 = {0.0f, 0.0f, 0.0f, 0.0f};
    const int stj[6] = {0, 0, 0, 1, 2, 4};   // first needed n-tile per layer

    // persistent skip accumulator: rows wm*64+mt*16+quad*4+r, cols sn*16+n16
    f32x4 sacc[4][4];
    #pragma unroll
    for (int mt = 0; mt < 4; ++mt)
        #pragma unroll
        for (int sn = 0; sn < 4; ++sn) sacc[mt][sn] = zero4;

    for (int j = 0; j < 6; ++j) {
        const int l = L0 + j;
        const int d = 1 << j;

        // stage cond(+bias): 3 coalesced 512B rows from zt
        for (int idx = tid; idx < 384; idx += 256) {
            int qq = idx >> 7, oo = idx & 127;
            int q = q0 + qq; if (q > 255) q = 255;
            zs[qq][oo] = zt[((size_t)(b * 256 + q)) * 3072 + l * 128 + oo];
        }
        // A1 fragments for m-tile wm (tanh) and wm+4 (sigmoid)
        bf16x8 a1a[4], a1b[4];
        #pragma unroll
        for (int ks = 0; ks < 4; ++ks) {
            a1a[ks] = A1v[((l * 8 + wm) * 4 + ks) * 64 + lane];
            a1b[ks] = A1v[((l * 8 + 4 + wm) * 4 + ks) * 64 + lane];
        }
        __syncthreads();   // A: zs staged + prev res writes done

        // GEMM1 + gate over needed n-tiles
        for (int nt = stj[j]; nt < 8; ++nt) {
            int nn = nt * 16 + n16;
            int rm = (nn >= d) ? nn - d : 0;
            bf16x8 b0 = *(const bf16x8*)&xh[rm][quad * 8];
            bf16x8 b1 = *(const bf16x8*)&xh[rm][32 + quad * 8];
            bf16x8 b2 = *(const bf16x8*)&xh[nn][quad * 8];
            bf16x8 b3 = *(const bf16x8*)&xh[nn][32 + quad * 8];
            f32x4 aa = zero4, ab = zero4;
            aa = mfma16(a1a[0], b0, aa); ab = mfma16(a1b[0], b0, ab);
            aa = mfma16(a1a[1], b1, aa); ab = mfma16(a1b[1], b1, ab);
            aa = mfma16(a1a[2], b2, aa); ab = mfma16(a1b[2], b2, ab);
            aa = mfma16(a1a[3], b3, aa); ab = mfma16(a1b[3], b3, ab);

            int tt = t0 - HALO + nn;
            int qq = ((tt > 0) ? tt : 0) / 75 - q0;
            int o0 = wm * 16 + quad * 4;
            f32x4 za = *(const f32x4*)&zs[qq][o0];
            f32x4 zb = *(const f32x4*)&zs[qq][o0 + 64];
            bf16x4 g4;
            #pragma unroll
            for (int r = 0; r < 4; ++r) {
                float ya = aa[r] + za[r];
                float yb = ab[r] + zb[r];
                float th = 1.0f - 2.0f * __builtin_amdgcn_rcpf(__expf(2.0f * ya) + 1.0f);
                float sg = __builtin_amdgcn_rcpf(1.0f + __expf(-yb));
                g4[r] = (__bf16)(th * sg);
            }
            *(bf16x4*)&Gs[nn][o0] = g4;
        }
        __syncthreads();   // B: Gs complete

        // skip GEMM: accumulate into persistent registers (valid tiles 4..7)
        #pragma unroll
        for (int ks = 0; ks < 2; ++ks) {
            bf16x8 bfr[4];
            #pragma unroll
            for (int sn = 0; sn < 4; ++sn)
                bfr[sn] = *(const bf16x8*)&Gs[HALO + sn * 16 + n16][ks * 32 + quad * 8];
            #pragma unroll
            for (int mt = 0; mt < 4; ++mt) {
                bf16x8 af = Asv[((l * 16 + wm * 4 + mt) * 2 + ks) * 64 + lane];
                #pragma unroll
                for (int sn = 0; sn < 4; ++sn)
                    sacc[mt][sn] = mfma16(af, bfr[sn], sacc[mt][sn]);
            }
        }

        // residual: x += res_w @ g + res_b (needed tiles only, in LDS)
        if (l < NLAYER - 1) {
            bf16x8 a3[2];
            #pragma unroll
            for (int ks = 0; ks < 2; ++ks)
                a3[ks] = A3v[((l * 4 + wm) * 2 + ks) * 64 + lane];
            int o0 = wm * 16 + quad * 4;
            f32x4 rb = *(const f32x4*)&res_b[l * 64 + o0];
            for (int nt = stj[j]; nt < 8; ++nt) {
                int nn = nt * 16 + n16;
                bf16x8 g0 = *(const bf16x8*)&Gs[nn][quad * 8];
                bf16x8 g1 = *(const bf16x8*)&Gs[nn][32 + quad * 8];
                f32x4 ar = zero4;
                ar = mfma16(a3[0], g0, ar);
                ar = mfma16(a3[1], g1, ar);
                bf16x4 xo = *(const bf16x4*)&xh[nn][o0];
                bf16x4 xn;
                #pragma unroll
                for (int r = 0; r < 4; ++r)
                    xn[r] = (__bf16)((float)xo[r] + ar[r] + rb[r]);
                *(bf16x4*)&xh[nn][o0] = xn;
            }
        }
        // next iteration's sync A orders these writes vs next GEMM1 reads
    }

    // ---- write skip partial (bf16) for this layer group ----
    #pragma unroll
    for (int mt = 0; mt < 4; ++mt) {
        int s0 = wm * 64 + mt * 16 + quad * 4;
        #pragma unroll
        for (int sn = 0; sn < 4; ++sn) {
            int t = t0 + sn * 16 + n16;
            #pragma unroll
            for (int r = 0; r < 4; ++r)
                skipp_g[((size_t)(b * SKIPN + s0 + r)) * T_TOT + t] =
                    (__bf16)sacc[mt][sn][r];
        }
    }

    if (!last) {
        __syncthreads();
        for (int idx = tid; idx < 512; idx += 256) {
            int rr = idx >> 3, hc = (idx & 7) * 8;
            *(bf16x8*)&xg_out[((size_t)b * T_TOT + t0 + rr) * 64 + hc] =
                *(const bf16x8*)&xh[HALO + rr][hc];
        }
    }
}

// ---------------- head: sum partials + relu -> W1 -> relu -> W2 -> log-softmax ----
__global__ __launch_bounds__(256, 4) void head_mfma(
    const __bf16* __restrict__ skipp, const float* __restrict__ sbsum,
    const __bf16* __restrict__ Ao1f, const __bf16* __restrict__ Ao2f,
    float* __restrict__ out)
{
    __shared__ __bf16 Vs[NOH][264];
    __shared__ float redm[4][2][16];
    __shared__ float reds[4][2][16];

    const int b    = blockIdx.y;
    const int t0   = blockIdx.x * NOH;
    const int tid  = threadIdx.x;
    const int lane = tid & 63;
    const int w    = tid >> 6;
    const int n16  = lane & 15;
    const int quad = lane >> 4;

    // phase 1: Vs[t][s] = relu(sum_g skipp[g] + sbsum)
    for (int idx = tid; idx < SKIPN * NOH; idx += 256) {
        int s = idx >> 5, tl = idx & 31;
        size_t off = ((size_t)(b * SKIPN + s)) * T_TOT + t0 + tl;
        float v = sbsum[s] + (float)skipp[off] + (float)skipp[off + PSTRIDE] +
                  (float)skipp[off + 2 * PSTRIDE] + (float)skipp[off + 3 * PSTRIDE];
        Vs[tl][s] = (__bf16)fmaxf(v, 0.0f);
    }
    __syncthreads();

    f32x4 zero4 = {0.0f, 0.0f, 0.0f, 0.0f};
    f32x4 acc[4][2];
    const bf16x8* W1v = (const bf16x8*)Ao1f;
    const bf16x8* W2v = (const bf16x8*)Ao2f;

    // phase 2: h1 = relu(W1 @ v), K=256
    #pragma unroll
    for (int mt = 0; mt < 4; ++mt)
        #pragma unroll
        for (int nt = 0; nt < 2; ++nt) acc[mt][nt] = zero4;
    #pragma unroll
    for (int ks = 0; ks < 8; ++ks) {
        bf16x8 bfr[2];
        #pragma unroll
        for (int nt = 0; nt < 2; ++nt)
            bfr[nt] = *(const bf16x8*)&Vs[nt * 16 + n16][ks * 32 + quad * 8];
        #pragma unroll
        for (int mt = 0; mt < 4; ++mt) {
            bf16x8 af = W1v[((w * 4 + mt) * 8 + ks) * 64 + lane];
            #pragma unroll
            for (int nt = 0; nt < 2; ++nt)
                acc[mt][nt] = mfma16(af, bfr[nt], acc[mt][nt]);
        }
    }
    __syncthreads();   // all Vs reads done; safe to overwrite
    #pragma unroll
    for (int mt = 0; mt < 4; ++mt)
        #pragma unroll
        for (int nt = 0; nt < 2; ++nt) {
            int o0 = w * 64 + mt * 16 + quad * 4;
            bf16x4 v4;
            #pragma unroll
            for (int r = 0; r < 4; ++r)
                v4[r] = (__bf16)fmaxf(acc[mt][nt][r], 0.0f);
            *(bf16x4*)&Vs[nt * 16 + n16][o0] = v4;
        }
    __syncthreads();

    // phase 3: h2 = W2 @ relu(h1)
    #pragma unroll
    for (int mt = 0; mt < 4; ++mt)
        #pragma unroll
        for (int nt = 0; nt < 2; ++nt) acc[mt][nt] = zero4;
    #pragma unroll
    for (int ks = 0; ks < 8; ++ks) {
        bf16x8 bfr[2];
        #pragma unroll
        for (int nt = 0; nt < 2; ++nt)
            bfr[nt] = *(const bf16x8*)&Vs[nt * 16 + n16][ks * 32 + quad * 8];
        #pragma unroll
        for (int mt = 0; mt < 4; ++mt) {
            bf16x8 af = W2v[((w * 4 + mt) * 8 + ks) * 64 + lane];
            #pragma unroll
            for (int nt = 0; nt < 2; ++nt)
                acc[mt][nt] = mfma16(af, bfr[nt], acc[mt][nt]);
        }
    }

    // log-softmax over 256 channels per column
    float lmax[2], lsum[2];
    #pragma unroll
    for (int nt = 0; nt < 2; ++nt) {
        float m = -1e30f;
        #pragma unroll
        for (int mt = 0; mt < 4; ++mt)
            #pragma unroll
            for (int r = 0; r < 4; ++r) m = fmaxf(m, acc[mt][nt][r]);
        m = fmaxf(m, __shfl_xor(m, 16, 64));
        m = fmaxf(m, __shfl_xor(m, 32, 64));
        lmax[nt] = m;
    }
    if (quad == 0) {
        #pragma unroll
        for (int nt = 0; nt < 2; ++nt) redm[w][nt][n16] = lmax[nt];
    }
    __syncthreads();
    #pragma unroll
    for (int nt = 0; nt < 2; ++nt) {
        float m = redm[0][nt][n16];
        m = fmaxf(m, redm[1][nt][n16]);
        m = fmaxf(m, redm[2][nt][n16]);
        m = fmaxf(m, redm[3][nt][n16]);
        lmax[nt] = m;
        float s = 0.0f;
        #pragma unroll
        for (int mt = 0; mt < 4; ++mt)
            #pragma unroll
            for (int r = 0; r < 4; ++r) s += __expf(acc[mt][nt][r] - m);
        s += __shfl_xor(s, 16, 64);
        s += __shfl_xor(s, 32, 64);
        lsum[nt] = s;
    }
    if (quad == 0) {
        #pragma unroll
        for (int nt = 0; nt < 2; ++nt) reds[w][nt][n16] = lsum[nt];
    }
    __syncthreads();
    #pragma unroll
    for (int nt = 0; nt < 2; ++nt) {
        float s = reds[0][nt][n16] + reds[1][nt][n16] +
                  reds[2][nt][n16] + reds[3][nt][n16];
        float lse = lmax[nt] + logf(s);
        int t = t0 + nt * 16 + n16;
        #pragma unroll
        for (int mt = 0; mt < 4; ++mt)
            #pragma unroll
            for (int r = 0; r < 4; ++r) {
                int o = w * 64 + mt * 16 + quad * 4 + r;
                out[((size_t)(b * SKIPN + o)) * T_TOT + t] = acc[mt][nt][r] - lse;
            }
    }
}

extern "C" void kernel_launch(void* const* d_in, const int* in_sizes, int n_in,
                              void* d_out, int out_size, void* d_ws, size_t ws_size,
                              hipStream_t stream) {
    const float* lf       = (const float*)d_in[0];
    const float* gold     = (const float*)d_in[1];
    const float* embed_w  = (const float*)d_in[2];
    const float* embed_b  = (const float*)d_in[3];
    const float* up_w     = (const float*)d_in[4];
    const float* up_b     = (const float*)d_in[5];
    const float* proj_w   = (const float*)d_in[6];
    const float* proj_b   = (const float*)d_in[7];
    const float* dil_w    = (const float*)d_in[8];
    const float* dil_b    = (const float*)d_in[9];
    const float* skip_w   = (const float*)d_in[10];
    const float* skip_b   = (const float*)d_in[11];
    const float* res_w    = (const float*)d_in[12];
    const float* res_b    = (const float*)d_in[13];
    const float* out1_w   = (const float*)d_in[14];
    const float* out2_w   = (const float*)d_in[15];

    __bf16* A1f  = (__bf16*)d_ws;          // 393216
    __bf16* Asf  = A1f + 393216;           // 393216
    __bf16* A3f  = Asf + 393216;           // 94208
    __bf16* Ao1f = A3f + 94208;            // 65536
    __bf16* Ao2f = Ao1f + 65536;           // 65536
    __bf16* xga  = Ao2f + 65536;           // 2457600
    __bf16* xgb  = xga + (size_t)NB * T_TOT * HD;          // 2457600
    float*  sbsum = (float*)(xgb + (size_t)NB * T_TOT * HD);
    float*  y_up  = sbsum + 256;
    float*  zt    = y_up + NB * LFN * 256;                 // 2*256*3072 f32
    __bf16* skipp = (__bf16*)(zt + NB * 256 * 3072);       // 4 * PSTRIDE bf16
    // z (prologue-only) aliases the skipp region: consumed by ztrans before
    // any layer_group writes skipp.
    float*  z     = (float*)skipp;                          // 2*3072*256 f32

    prep_kernel<<<(24 * 128 * 128 + 255) / 256, 256, 0, stream>>>(
        dil_w, skip_w, skip_b, res_w, out1_w, out2_w,
        A1f, Asf, A3f, Ao1f, Ao2f, sbsum);
    up_kernel  <<<(NB * LFN * 256 + 255) / 256, 256, 0, stream>>>(lf, up_w, up_b, y_up);
    proj_kernel<<<(NB * 3072 * 256) / 256,      256, 0, stream>>>(y_up, proj_w, proj_b, z);
    ztrans_kernel<<<dim3(96, 8, NB), 256, 0, stream>>>(z, dil_b, zt);

    const __bf16* xin[4] = { xga, xga, xgb, xga };
    __bf16*       xout[4] = { xga, xgb, xga, xgb };
    for (int g = 0; g < 4; ++g) {
        layer_group<<<dim3(NGT, NB), 256, 0, stream>>>(
            gold, embed_w, embed_b, xin[g], xout[g],
            zt, res_b, A1f, A3f, Asf, skipp + (size_t)g * PSTRIDE,
            6 * g, (g == 0) ? 1 : 0, (g == 3) ? 1 : 0);
    }

    head_mfma<<<dim3(NTH, NB), 256, 0, stream>>>(skipp, sbsum, Ao1f, Ao2f, (float*)d_out);
}